// Round 5
// baseline (449.178 us; speedup 1.0000x reference)
//
#include <hip/hip_runtime.h>

// ---------------------------------------------------------------------------
// Attention block on MI355X (gfx950), bf16-MFMA pipeline.
// R5: fuse Q/K/V projections into one GEMM (N=6144, grid 1536, XCD swizzle);
// attn gets T13 defer-rescale. Out-proj GEMM gets XCD swizzle.
// ---------------------------------------------------------------------------

typedef unsigned short u16;
using bf16x8 = __attribute__((ext_vector_type(8))) short;   // 8 bf16 (4 VGPRs)
using f32x4  = __attribute__((ext_vector_type(4))) float;
using u16x8  = __attribute__((ext_vector_type(8))) unsigned short;
using u16x4  = __attribute__((ext_vector_type(4))) unsigned short;

#define AS1 __attribute__((address_space(1)))
#define AS3 __attribute__((address_space(3)))

__device__ __forceinline__ u16 f2bf(float f) {
    union { float f; unsigned u; } v; v.f = f;
    unsigned r = v.u + 0x7fffu + ((v.u >> 16) & 1u);   // RNE
    return (u16)(r >> 16);
}

__device__ __forceinline__ void gload_lds16(const void* g, void* l) {
    __builtin_amdgcn_global_load_lds((const AS1 void*)g, (AS3 void*)l, 16, 0, 0);
}

// ---------------- x -> bf16 ----------------
__global__ __launch_bounds__(256) void cvt_x_k(const float* __restrict__ x,
                                               u16* __restrict__ xb) {
    int i = (blockIdx.x * 256 + threadIdx.x) * 4;
    float4 v = *(const float4*)(x + i);
    u16x4 o;
    o[0] = f2bf(v.x); o[1] = f2bf(v.y); o[2] = f2bf(v.z); o[3] = f2bf(v.w);
    *(u16x4*)(xb + i) = o;
}

// ---------------- weights -> bf16, transposed (WT[n][k]) ----------------
__global__ __launch_bounds__(256) void wcvt_k(const float* __restrict__ Wq,
                                              const float* __restrict__ Wk,
                                              const float* __restrict__ Wv,
                                              const float* __restrict__ Wo,
                                              u16* __restrict__ wt) {
    __shared__ float tile[32][33];
    const int z = blockIdx.z;
    const float* W = (z == 0) ? Wq : (z == 1) ? Wk : (z == 2) ? Wv : Wo;
    const float scale = (z == 0) ? 0.12751744f : 1.0f;  // (1/sqrt(128))*log2(e)
    const int tx = threadIdx.x, ty = threadIdx.y;       // block (32,8)
    const int k0 = blockIdx.x * 32, n0 = blockIdx.y * 32;
#pragma unroll
    for (int j = 0; j < 4; j++)
        tile[ty + j * 8][tx] = W[(size_t)(k0 + ty + j * 8) * 2048 + n0 + tx];
    __syncthreads();
    u16* dst = wt + (size_t)z * 4194304;
#pragma unroll
    for (int j = 0; j < 4; j++)
        dst[(size_t)(n0 + ty + j * 8) * 2048 + k0 + tx] = f2bf(tile[tx][ty + j * 8] * scale);
}

// ---------------- fused QKV GEMM ----------------
// C(4096 x 6144) = xb(4096x2048) * wt(6144x2048)^T ; m97 structure, 128x128.
// n < 4096  -> qkb[m][n]         (Q*scale | K)
// n >= 4096 -> vtb[n-4096][m]    (V^T)
// 1536 blocks (1D), XCD-swizzled decode.
__global__ __launch_bounds__(256) void gemm_qkv_k(const u16* __restrict__ A,
                                                  const u16* __restrict__ BT,
                                                  u16* __restrict__ qkb,
                                                  u16* __restrict__ vtb) {
    __shared__ u16 As[4096];   // [128][32]
    __shared__ u16 Bs[4096];   // [128][32]
    const int bid = blockIdx.x;
    const int swz = (bid & 7) * 192 + (bid >> 3);   // 1536 = 8 * 192, bijective
    const int bx = swz & 31, by = swz >> 5;         // bx: m-tile, by: n-tile
    const int tid = threadIdx.x, ln = tid & 63, w = tid >> 6;
    const int m0 = bx * 128, n0 = by * 128;
    f32x4 acc[4][4] = {};

    const int e0 = w * 512 + ln * 8;
    const int e1 = (4 + w) * 512 + ln * 8;
    const int ar0 = e0 >> 5, ac0 = e0 & 31;
    const int ar1 = e1 >> 5, ac1 = e1 & 31;
    const u16* Ag0 = A + (size_t)(m0 + ar0) * 2048 + ac0;
    const u16* Ag1 = A + (size_t)(m0 + ar1) * 2048 + ac1;
    const u16* Bg0 = BT + (size_t)(n0 + ar0) * 2048 + ac0;
    const u16* Bg1 = BT + (size_t)(n0 + ar1) * 2048 + ac1;
    u16* As0 = As + w * 512;  u16* As1 = As + (4 + w) * 512;
    u16* Bs0 = Bs + w * 512;  u16* Bs1 = Bs + (4 + w) * 512;

    const int mb = (w >> 1) * 64, nb = (w & 1) * 64;

    for (int k0 = 0; k0 < 2048; k0 += 32) {
        __syncthreads();
        gload_lds16(Ag0 + k0, As0);
        gload_lds16(Ag1 + k0, As1);
        gload_lds16(Bg0 + k0, Bs0);
        gload_lds16(Bg1 + k0, Bs1);
        __syncthreads();
        bf16x8 a[4], b[4];
#pragma unroll
        for (int i = 0; i < 4; i++)
            a[i] = *(const bf16x8*)(As + (mb + i * 16 + (ln & 15)) * 32 + (ln >> 4) * 8);
#pragma unroll
        for (int i = 0; i < 4; i++)
            b[i] = *(const bf16x8*)(Bs + (nb + i * 16 + (ln & 15)) * 32 + (ln >> 4) * 8);
#pragma unroll
        for (int i = 0; i < 4; i++)
#pragma unroll
            for (int j = 0; j < 4; j++)
                acc[i][j] = __builtin_amdgcn_mfma_f32_16x16x32_bf16(a[i], b[j], acc[i][j], 0, 0, 0);
    }

    if (n0 < 4096) {   // Q|K epilogue -> qkb [m][n], ldc 4096
#pragma unroll
        for (int i = 0; i < 4; i++)
#pragma unroll
            for (int j = 0; j < 4; j++)
#pragma unroll
                for (int r = 0; r < 4; r++)
                    qkb[(size_t)(m0 + mb + i * 16 + (ln >> 4) * 4 + r) * 4096 +
                        (n0 + nb + j * 16 + (ln & 15))] = f2bf(acc[i][j][r]);
    } else {           // V epilogue -> vtb [n-4096][m], ldc 4096 (transposed)
        const int n0r = n0 - 4096;
#pragma unroll
        for (int i = 0; i < 4; i++)
#pragma unroll
            for (int j = 0; j < 4; j++) {
                u16x4 pk;
#pragma unroll
                for (int r = 0; r < 4; r++) pk[r] = f2bf(acc[i][j][r]);
                *(u16x4*)(vtb + (size_t)(n0r + nb + j * 16 + (ln & 15)) * 4096 +
                          (m0 + mb + i * 16 + (ln >> 4) * 4)) = pk;
            }
    }
}

// ---------------- out-proj GEMM (f32 out), m97 structure ----------------
__global__ __launch_bounds__(256) void gemm_out_k(const u16* __restrict__ A,
                                                  const u16* __restrict__ BT,
                                                  float* __restrict__ C) {
    __shared__ u16 As[4096];
    __shared__ u16 Bs[4096];
    const int bid = blockIdx.x;
    const int swz = (bid & 7) * 64 + (bid >> 3);    // 512 = 8 * 64, bijective
    const int bx = swz & 31, by = swz >> 5;         // bx: m-tile (32), by: n-tile (16)
    const int tid = threadIdx.x, ln = tid & 63, w = tid >> 6;
    const int m0 = bx * 128, n0 = by * 128;
    f32x4 acc[4][4] = {};

    const int e0 = w * 512 + ln * 8;
    const int e1 = (4 + w) * 512 + ln * 8;
    const int ar0 = e0 >> 5, ac0 = e0 & 31;
    const int ar1 = e1 >> 5, ac1 = e1 & 31;
    const u16* Ag0 = A + (size_t)(m0 + ar0) * 2048 + ac0;
    const u16* Ag1 = A + (size_t)(m0 + ar1) * 2048 + ac1;
    const u16* Bg0 = BT + (size_t)(n0 + ar0) * 2048 + ac0;
    const u16* Bg1 = BT + (size_t)(n0 + ar1) * 2048 + ac1;
    u16* As0 = As + w * 512;  u16* As1 = As + (4 + w) * 512;
    u16* Bs0 = Bs + w * 512;  u16* Bs1 = Bs + (4 + w) * 512;

    const int mb = (w >> 1) * 64, nb = (w & 1) * 64;

    for (int k0 = 0; k0 < 2048; k0 += 32) {
        __syncthreads();
        gload_lds16(Ag0 + k0, As0);
        gload_lds16(Ag1 + k0, As1);
        gload_lds16(Bg0 + k0, Bs0);
        gload_lds16(Bg1 + k0, Bs1);
        __syncthreads();
        bf16x8 a[4], b[4];
#pragma unroll
        for (int i = 0; i < 4; i++)
            a[i] = *(const bf16x8*)(As + (mb + i * 16 + (ln & 15)) * 32 + (ln >> 4) * 8);
#pragma unroll
        for (int i = 0; i < 4; i++)
            b[i] = *(const bf16x8*)(Bs + (nb + i * 16 + (ln & 15)) * 32 + (ln >> 4) * 8);
#pragma unroll
        for (int i = 0; i < 4; i++)
#pragma unroll
            for (int j = 0; j < 4; j++)
                acc[i][j] = __builtin_amdgcn_mfma_f32_16x16x32_bf16(a[i], b[j], acc[i][j], 0, 0, 0);
    }

#pragma unroll
    for (int i = 0; i < 4; i++)
#pragma unroll
        for (int j = 0; j < 4; j++)
#pragma unroll
            for (int r = 0; r < 4; r++)
                C[(size_t)(m0 + mb + i * 16 + (ln >> 4) * 4 + r) * 2048 +
                  (n0 + nb + j * 16 + (ln & 15))] = acc[i][j][r];
}

// ---------------- flash attention v3 (v2 + T13 defer-rescale) ----------------
// qk: (4096)x4096 bf16, cols [0,2048)=Q*scale(log2e), [2048,4096)=K
// vt: (2048 = h*128+d) x 4096 bf16  (V^T)
// ctx: (4096)x2048 bf16
__global__ __launch_bounds__(256, 2) void attn_k(const u16* __restrict__ qk,
                                                 const u16* __restrict__ vt,
                                                 u16* __restrict__ ctx) {
    const int bid = blockIdx.x;
    const int xcd = bid & 7, idx = bid >> 3;     // XCD-grouped decode
    const int bh = xcd * 4 + (idx & 3);          // 4 (b,h) groups per XCD
    const int qp = idx >> 2;                     // 0..15
    const int b = bh >> 4, h = bh & 15;
    const int qtA = qp, qtB = 31 - qp;
    const int tid = threadIdx.x, ln = tid & 63, w = tid >> 6;

    __shared__ u16 Ks[2][8192];     // [64][128] bf16, XOR-swizzled
    __shared__ u16 Vs[2][8192];     // [128][64] bf16, XOR-swizzled
    __shared__ u16 Pl[4][16 * 72];  // per-wave P tile [q][kv], pad 8

    const u16* Kg = qk + (size_t)(b * 2048) * 4096 + 2048 + h * 128;  // +t*4096+d
    const u16* Vg = vt + (size_t)(h * 128) * 4096 + b * 2048;         // +d*4096+t

    const int nstA = qtA + 1;
    const int nst = 33;

    const int skr = tid >> 4, skc = (tid & 15) * 8;   // K: row skr+p*16, col skc
    const int svd = tid >> 3, svc = (tid & 7) * 8;    // V: d svd+p*32, col svc

    u16x8 rg[8];
    auto issue = [&](int s) {
        const int kv0 = (s < nstA ? s : s - nstA) * 64;
#pragma unroll
        for (int p = 0; p < 4; ++p)
            rg[p] = *(const u16x8*)(Kg + (size_t)(kv0 + p * 16 + skr) * 4096 + skc);
#pragma unroll
        for (int p = 0; p < 4; ++p)
            rg[4 + p] = *(const u16x8*)(Vg + (size_t)(p * 32 + svd) * 4096 + kv0 + svc);
    };
    auto writebuf = [&](int bi) {
#pragma unroll
        for (int p = 0; p < 4; ++p) {
            int r = p * 16 + skr;
            int by = (r * 256 + skc * 2) ^ ((r & 7) << 4);
            *(u16x8*)((char*)Ks[bi] + by) = rg[p];
        }
#pragma unroll
        for (int p = 0; p < 4; ++p) {
            int d = p * 32 + svd;
            int by = (d * 128 + svc * 2) ^ ((d & 7) << 4);
            *(u16x8*)((char*)Vs[bi] + by) = rg[4 + p];
        }
    };

    issue(0);
    writebuf(0);
    __syncthreads();
    int cur = 0, s = 0;

    for (int t = 0; t < 2; ++t) {
        const int qt = (t == 0) ? qtA : qtB;
        const int q0w = qt * 64 + w * 16;
        bf16x8 qf[4];
        {
            const u16* qb = qk + (size_t)(b * 2048 + q0w + (ln & 15)) * 4096 +
                            h * 128 + (ln >> 4) * 8;
#pragma unroll
            for (int kc = 0; kc < 4; ++kc) qf[kc] = *(const bf16x8*)(qb + kc * 32);
        }
        f32x4 o[8] = {};
        float mref[4], lsum[4];
#pragma unroll
        for (int r = 0; r < 4; ++r) { mref[r] = -3.0e38f; lsum[r] = 0.f; }

        for (int kb = 0; kb <= qt; ++kb, ++s) {
            const bool more = (s + 1 < nst);
            if (more) issue(s + 1);          // prefetch next tile into regs
            const int kv0 = kb * 64;

            // S = Q K^T (16 q-rows x 64 kv per wave), log2 domain
            f32x4 sv[4] = {};
            __builtin_amdgcn_s_setprio(1);
#pragma unroll
            for (int kc = 0; kc < 4; ++kc)
#pragma unroll
                for (int nf = 0; nf < 4; ++nf) {
                    int row = nf * 16 + (ln & 15);
                    int by = (row * 256 + kc * 64 + (ln >> 4) * 16) ^ ((row & 7) << 4);
                    bf16x8 kf = *(const bf16x8*)((const char*)Ks[cur] + by);
                    sv[nf] = __builtin_amdgcn_mfma_f32_16x16x32_bf16(qf[kc], kf, sv[nf], 0, 0, 0);
                }
            __builtin_amdgcn_s_setprio(0);

            if (kb == qt) {  // causal mask on diagonal block
#pragma unroll
                for (int nf = 0; nf < 4; ++nf) {
                    int kva = kv0 + nf * 16 + (ln & 15);
#pragma unroll
                    for (int r = 0; r < 4; r++) {
                        int qa = q0w + (ln >> 4) * 4 + r;
                        if (kva > qa) sv[nf][r] = -3.0e38f;
                    }
                }
            }

            // online softmax with T13 defer-rescale (THR = 8 in log2 domain)
#pragma unroll
            for (int r = 0; r < 4; r++) {
                float rm = fmaxf(fmaxf(sv[0][r], sv[1][r]), fmaxf(sv[2][r], sv[3][r]));
                rm = fmaxf(rm, __shfl_xor(rm, 1));
                rm = fmaxf(rm, __shfl_xor(rm, 2));
                rm = fmaxf(rm, __shfl_xor(rm, 4));
                rm = fmaxf(rm, __shfl_xor(rm, 8));
                if (rm > mref[r] + 8.0f) {   // rescale only on real growth
                    float sc = exp2f(mref[r] - rm);
                    mref[r] = rm;
                    lsum[r] *= sc;
#pragma unroll
                    for (int df = 0; df < 8; ++df) o[df][r] *= sc;
                }
                float rs = 0.f;
#pragma unroll
                for (int nf = 0; nf < 4; ++nf) {
                    float p = exp2f(sv[nf][r] - mref[r]);   // bounded by 2^8
                    sv[nf][r] = p;
                    rs += p;
                }
                rs += __shfl_xor(rs, 1); rs += __shfl_xor(rs, 2);
                rs += __shfl_xor(rs, 4); rs += __shfl_xor(rs, 8);
                lsum[r] += rs;
            }

            // P -> per-wave LDS (bf16), then PV
            u16* pw = Pl[w];
#pragma unroll
            for (int nf = 0; nf < 4; ++nf)
#pragma unroll
                for (int r = 0; r < 4; r++)
                    pw[((ln >> 4) * 4 + r) * 72 + nf * 16 + (ln & 15)] = f2bf(sv[nf][r]);

#pragma unroll
            for (int kc = 0; kc < 2; ++kc) {
                bf16x8 a = *(const bf16x8*)(pw + (ln & 15) * 72 + kc * 32 + (ln >> 4) * 8);
                __builtin_amdgcn_s_setprio(1);
#pragma unroll
                for (int df = 0; df < 8; ++df) {
                    int d = df * 16 + (ln & 15);
                    int by = (d * 128 + kc * 64 + (ln >> 4) * 16) ^ ((d & 7) << 4);
                    bf16x8 vb = *(const bf16x8*)((const char*)Vs[cur] + by);
                    o[df] = __builtin_amdgcn_mfma_f32_16x16x32_bf16(a, vb, o[df], 0, 0, 0);
                }
                __builtin_amdgcn_s_setprio(0);
            }

            if (more) {
                __syncthreads();
                writebuf(cur ^ 1);
                __syncthreads();
                cur ^= 1;
            }
        }

        // finalize tile t
#pragma unroll
        for (int r = 0; r < 4; ++r) lsum[r] = 1.0f / lsum[r];
#pragma unroll
        for (int df = 0; df < 8; ++df)
#pragma unroll
            for (int r = 0; r < 4; r++) {
                int qa = q0w + (ln >> 4) * 4 + r;
                ctx[(size_t)(b * 2048 + qa) * 2048 + h * 128 + df * 16 + (ln & 15)] =
                    f2bf(o[df][r] * lsum[r]);
            }
    }
}

// ---------------------------------------------------------------------------
extern "C" void kernel_launch(void* const* d_in, const int* in_sizes, int n_in,
                              void* d_out, int out_size, void* d_ws, size_t ws_size,
                              hipStream_t stream) {
    const float* x  = (const float*)d_in[0];
    const float* wq = (const float*)d_in[1];
    const float* wk = (const float*)d_in[2];
    const float* wv = (const float*)d_in[3];
    const float* wo = (const float*)d_in[4];
    float* out = (float*)d_out;

    u16* ws  = (u16*)d_ws;
    u16* xb  = ws;                     //  8,388,608 : x bf16 (4096x2048)
    u16* wt  = xb + 8388608;           // 16,777,216 : WqT|WkT|WvT|WoT bf16
    u16* qkb = wt + 16777216;          // 16,777,216 : [Q*scale | K] (4096x4096)
    u16* vtb = qkb + 16777216;         //  8,388,608 : V^T (2048x4096)
    u16* ctx = vtb + 8388608;          //  8,388,608 : attention out (4096x2048)

    cvt_x_k<<<8192, 256, 0, stream>>>(x, xb);
    wcvt_k<<<dim3(64, 64, 4), dim3(32, 8), 0, stream>>>(wq, wk, wv, wo, wt);
    gemm_qkv_k<<<1536, 256, 0, stream>>>(xb, wt, qkb, vtb);      // Q|K|V fused
    attn_k<<<512, 256, 0, stream>>>(qkb, vtb, ctx);
    gemm_out_k<<<512, 256, 0, stream>>>(ctx, wt + 3 * 4194304, out);
}

// Round 6
// 439.692 us; speedup vs baseline: 1.0216x; 1.0216x over previous
//
#include <hip/hip_runtime.h>

// ---------------------------------------------------------------------------
// Attention block on MI355X (gfx950), bf16-MFMA pipeline.
// R6: revert XCD swizzle on GEMMs (L3-resident workload; swizzle caused 5x
// A-refetch, FETCH 209MB). Natural 2D grids. Keep QKV fusion + attn T13.
// ---------------------------------------------------------------------------

typedef unsigned short u16;
using bf16x8 = __attribute__((ext_vector_type(8))) short;   // 8 bf16 (4 VGPRs)
using f32x4  = __attribute__((ext_vector_type(4))) float;
using u16x8  = __attribute__((ext_vector_type(8))) unsigned short;
using u16x4  = __attribute__((ext_vector_type(4))) unsigned short;

#define AS1 __attribute__((address_space(1)))
#define AS3 __attribute__((address_space(3)))

__device__ __forceinline__ u16 f2bf(float f) {
    union { float f; unsigned u; } v; v.f = f;
    unsigned r = v.u + 0x7fffu + ((v.u >> 16) & 1u);   // RNE
    return (u16)(r >> 16);
}

__device__ __forceinline__ void gload_lds16(const void* g, void* l) {
    __builtin_amdgcn_global_load_lds((const AS1 void*)g, (AS3 void*)l, 16, 0, 0);
}

// ---------------- x -> bf16 ----------------
__global__ __launch_bounds__(256) void cvt_x_k(const float* __restrict__ x,
                                               u16* __restrict__ xb) {
    int i = (blockIdx.x * 256 + threadIdx.x) * 4;
    float4 v = *(const float4*)(x + i);
    u16x4 o;
    o[0] = f2bf(v.x); o[1] = f2bf(v.y); o[2] = f2bf(v.z); o[3] = f2bf(v.w);
    *(u16x4*)(xb + i) = o;
}

// ---------------- weights -> bf16, transposed (WT[n][k]) ----------------
__global__ __launch_bounds__(256) void wcvt_k(const float* __restrict__ Wq,
                                              const float* __restrict__ Wk,
                                              const float* __restrict__ Wv,
                                              const float* __restrict__ Wo,
                                              u16* __restrict__ wt) {
    __shared__ float tile[32][33];
    const int z = blockIdx.z;
    const float* W = (z == 0) ? Wq : (z == 1) ? Wk : (z == 2) ? Wv : Wo;
    const float scale = (z == 0) ? 0.12751744f : 1.0f;  // (1/sqrt(128))*log2(e)
    const int tx = threadIdx.x, ty = threadIdx.y;       // block (32,8)
    const int k0 = blockIdx.x * 32, n0 = blockIdx.y * 32;
#pragma unroll
    for (int j = 0; j < 4; j++)
        tile[ty + j * 8][tx] = W[(size_t)(k0 + ty + j * 8) * 2048 + n0 + tx];
    __syncthreads();
    u16* dst = wt + (size_t)z * 4194304;
#pragma unroll
    for (int j = 0; j < 4; j++)
        dst[(size_t)(n0 + ty + j * 8) * 2048 + k0 + tx] = f2bf(tile[tx][ty + j * 8] * scale);
}

// ---------------- fused QKV GEMM ----------------
// C(4096 x 6144) = xb(4096x2048) * wt(6144x2048)^T ; m97 structure, 128x128.
// grid dim3(32, 48): x = m-tile, y = n-tile (natural order; L3-resident).
// n < 4096  -> qkb[m][n]   (Q*scale | K);  n >= 4096 -> vtb[n-4096][m]  (V^T)
__global__ __launch_bounds__(256) void gemm_qkv_k(const u16* __restrict__ A,
                                                  const u16* __restrict__ BT,
                                                  u16* __restrict__ qkb,
                                                  u16* __restrict__ vtb) {
    __shared__ u16 As[4096];   // [128][32]
    __shared__ u16 Bs[4096];   // [128][32]
    const int tid = threadIdx.x, ln = tid & 63, w = tid >> 6;
    const int m0 = blockIdx.x * 128, n0 = blockIdx.y * 128;
    f32x4 acc[4][4] = {};

    const int e0 = w * 512 + ln * 8;
    const int e1 = (4 + w) * 512 + ln * 8;
    const int ar0 = e0 >> 5, ac0 = e0 & 31;
    const int ar1 = e1 >> 5, ac1 = e1 & 31;
    const u16* Ag0 = A + (size_t)(m0 + ar0) * 2048 + ac0;
    const u16* Ag1 = A + (size_t)(m0 + ar1) * 2048 + ac1;
    const u16* Bg0 = BT + (size_t)(n0 + ar0) * 2048 + ac0;
    const u16* Bg1 = BT + (size_t)(n0 + ar1) * 2048 + ac1;
    u16* As0 = As + w * 512;  u16* As1 = As + (4 + w) * 512;
    u16* Bs0 = Bs + w * 512;  u16* Bs1 = Bs + (4 + w) * 512;

    const int mb = (w >> 1) * 64, nb = (w & 1) * 64;

    for (int k0 = 0; k0 < 2048; k0 += 32) {
        __syncthreads();
        gload_lds16(Ag0 + k0, As0);
        gload_lds16(Ag1 + k0, As1);
        gload_lds16(Bg0 + k0, Bs0);
        gload_lds16(Bg1 + k0, Bs1);
        __syncthreads();
        bf16x8 a[4], b[4];
#pragma unroll
        for (int i = 0; i < 4; i++)
            a[i] = *(const bf16x8*)(As + (mb + i * 16 + (ln & 15)) * 32 + (ln >> 4) * 8);
#pragma unroll
        for (int i = 0; i < 4; i++)
            b[i] = *(const bf16x8*)(Bs + (nb + i * 16 + (ln & 15)) * 32 + (ln >> 4) * 8);
#pragma unroll
        for (int i = 0; i < 4; i++)
#pragma unroll
            for (int j = 0; j < 4; j++)
                acc[i][j] = __builtin_amdgcn_mfma_f32_16x16x32_bf16(a[i], b[j], acc[i][j], 0, 0, 0);
    }

    if (n0 < 4096) {   // Q|K epilogue -> qkb [m][n], ldc 4096
#pragma unroll
        for (int i = 0; i < 4; i++)
#pragma unroll
            for (int j = 0; j < 4; j++)
#pragma unroll
                for (int r = 0; r < 4; r++)
                    qkb[(size_t)(m0 + mb + i * 16 + (ln >> 4) * 4 + r) * 4096 +
                        (n0 + nb + j * 16 + (ln & 15))] = f2bf(acc[i][j][r]);
    } else {           // V epilogue -> vtb [n-4096][m] (transposed)
        const int n0r = n0 - 4096;
#pragma unroll
        for (int i = 0; i < 4; i++)
#pragma unroll
            for (int j = 0; j < 4; j++) {
                u16x4 pk;
#pragma unroll
                for (int r = 0; r < 4; r++) pk[r] = f2bf(acc[i][j][r]);
                *(u16x4*)(vtb + (size_t)(n0r + nb + j * 16 + (ln & 15)) * 4096 +
                          (m0 + mb + i * 16 + (ln >> 4) * 4)) = pk;
            }
    }
}

// ---------------- out-proj GEMM (f32 out), m97 structure, natural grid -----
__global__ __launch_bounds__(256) void gemm_out_k(const u16* __restrict__ A,
                                                  const u16* __restrict__ BT,
                                                  float* __restrict__ C) {
    __shared__ u16 As[4096];
    __shared__ u16 Bs[4096];
    const int tid = threadIdx.x, ln = tid & 63, w = tid >> 6;
    const int m0 = blockIdx.x * 128, n0 = blockIdx.y * 128;
    f32x4 acc[4][4] = {};

    const int e0 = w * 512 + ln * 8;
    const int e1 = (4 + w) * 512 + ln * 8;
    const int ar0 = e0 >> 5, ac0 = e0 & 31;
    const int ar1 = e1 >> 5, ac1 = e1 & 31;
    const u16* Ag0 = A + (size_t)(m0 + ar0) * 2048 + ac0;
    const u16* Ag1 = A + (size_t)(m0 + ar1) * 2048 + ac1;
    const u16* Bg0 = BT + (size_t)(n0 + ar0) * 2048 + ac0;
    const u16* Bg1 = BT + (size_t)(n0 + ar1) * 2048 + ac1;
    u16* As0 = As + w * 512;  u16* As1 = As + (4 + w) * 512;
    u16* Bs0 = Bs + w * 512;  u16* Bs1 = Bs + (4 + w) * 512;

    const int mb = (w >> 1) * 64, nb = (w & 1) * 64;

    for (int k0 = 0; k0 < 2048; k0 += 32) {
        __syncthreads();
        gload_lds16(Ag0 + k0, As0);
        gload_lds16(Ag1 + k0, As1);
        gload_lds16(Bg0 + k0, Bs0);
        gload_lds16(Bg1 + k0, Bs1);
        __syncthreads();
        bf16x8 a[4], b[4];
#pragma unroll
        for (int i = 0; i < 4; i++)
            a[i] = *(const bf16x8*)(As + (mb + i * 16 + (ln & 15)) * 32 + (ln >> 4) * 8);
#pragma unroll
        for (int i = 0; i < 4; i++)
            b[i] = *(const bf16x8*)(Bs + (nb + i * 16 + (ln & 15)) * 32 + (ln >> 4) * 8);
#pragma unroll
        for (int i = 0; i < 4; i++)
#pragma unroll
            for (int j = 0; j < 4; j++)
                acc[i][j] = __builtin_amdgcn_mfma_f32_16x16x32_bf16(a[i], b[j], acc[i][j], 0, 0, 0);
    }

#pragma unroll
    for (int i = 0; i < 4; i++)
#pragma unroll
        for (int j = 0; j < 4; j++)
#pragma unroll
            for (int r = 0; r < 4; r++)
                C[(size_t)(m0 + mb + i * 16 + (ln >> 4) * 4 + r) * 2048 +
                  (n0 + nb + j * 16 + (ln & 15))] = acc[i][j][r];
}

// ---------------- flash attention v3 (paired q-tiles + prefetch + T13) -----
// qk: (4096)x4096 bf16, cols [0,2048)=Q*scale(log2e), [2048,4096)=K
// vt: (2048 = h*128+d) x 4096 bf16  (V^T)
// ctx: (4096)x2048 bf16
__global__ __launch_bounds__(256, 2) void attn_k(const u16* __restrict__ qk,
                                                 const u16* __restrict__ vt,
                                                 u16* __restrict__ ctx) {
    const int bid = blockIdx.x;
    const int xcd = bid & 7, idx = bid >> 3;     // XCD-grouped decode
    const int bh = xcd * 4 + (idx & 3);          // 4 (b,h) groups per XCD
    const int qp = idx >> 2;                     // 0..15
    const int b = bh >> 4, h = bh & 15;
    const int qtA = qp, qtB = 31 - qp;
    const int tid = threadIdx.x, ln = tid & 63, w = tid >> 6;

    __shared__ u16 Ks[2][8192];     // [64][128] bf16, XOR-swizzled
    __shared__ u16 Vs[2][8192];     // [128][64] bf16, XOR-swizzled
    __shared__ u16 Pl[4][16 * 72];  // per-wave P tile [q][kv], pad 8

    const u16* Kg = qk + (size_t)(b * 2048) * 4096 + 2048 + h * 128;  // +t*4096+d
    const u16* Vg = vt + (size_t)(h * 128) * 4096 + b * 2048;         // +d*4096+t

    const int nstA = qtA + 1;
    const int nst = 33;

    const int skr = tid >> 4, skc = (tid & 15) * 8;   // K: row skr+p*16, col skc
    const int svd = tid >> 3, svc = (tid & 7) * 8;    // V: d svd+p*32, col svc

    u16x8 rg[8];
    auto issue = [&](int s) {
        const int kv0 = (s < nstA ? s : s - nstA) * 64;
#pragma unroll
        for (int p = 0; p < 4; ++p)
            rg[p] = *(const u16x8*)(Kg + (size_t)(kv0 + p * 16 + skr) * 4096 + skc);
#pragma unroll
        for (int p = 0; p < 4; ++p)
            rg[4 + p] = *(const u16x8*)(Vg + (size_t)(p * 32 + svd) * 4096 + kv0 + svc);
    };
    auto writebuf = [&](int bi) {
#pragma unroll
        for (int p = 0; p < 4; ++p) {
            int r = p * 16 + skr;
            int by = (r * 256 + skc * 2) ^ ((r & 7) << 4);
            *(u16x8*)((char*)Ks[bi] + by) = rg[p];
        }
#pragma unroll
        for (int p = 0; p < 4; ++p) {
            int d = p * 32 + svd;
            int by = (d * 128 + svc * 2) ^ ((d & 7) << 4);
            *(u16x8*)((char*)Vs[bi] + by) = rg[4 + p];
        }
    };

    issue(0);
    writebuf(0);
    __syncthreads();
    int cur = 0, s = 0;

    for (int t = 0; t < 2; ++t) {
        const int qt = (t == 0) ? qtA : qtB;
        const int q0w = qt * 64 + w * 16;
        bf16x8 qf[4];
        {
            const u16* qb = qk + (size_t)(b * 2048 + q0w + (ln & 15)) * 4096 +
                            h * 128 + (ln >> 4) * 8;
#pragma unroll
            for (int kc = 0; kc < 4; ++kc) qf[kc] = *(const bf16x8*)(qb + kc * 32);
        }
        f32x4 o[8] = {};
        float mref[4], lsum[4];
#pragma unroll
        for (int r = 0; r < 4; ++r) { mref[r] = -3.0e38f; lsum[r] = 0.f; }

        for (int kb = 0; kb <= qt; ++kb, ++s) {
            const bool more = (s + 1 < nst);
            if (more) issue(s + 1);          // prefetch next tile into regs
            const int kv0 = kb * 64;

            // S = Q K^T (16 q-rows x 64 kv per wave), log2 domain
            f32x4 sv[4] = {};
            __builtin_amdgcn_s_setprio(1);
#pragma unroll
            for (int kc = 0; kc < 4; ++kc)
#pragma unroll
                for (int nf = 0; nf < 4; ++nf) {
                    int row = nf * 16 + (ln & 15);
                    int by = (row * 256 + kc * 64 + (ln >> 4) * 16) ^ ((row & 7) << 4);
                    bf16x8 kf = *(const bf16x8*)((const char*)Ks[cur] + by);
                    sv[nf] = __builtin_amdgcn_mfma_f32_16x16x32_bf16(qf[kc], kf, sv[nf], 0, 0, 0);
                }
            __builtin_amdgcn_s_setprio(0);

            if (kb == qt) {  // causal mask on diagonal block
#pragma unroll
                for (int nf = 0; nf < 4; ++nf) {
                    int kva = kv0 + nf * 16 + (ln & 15);
#pragma unroll
                    for (int r = 0; r < 4; r++) {
                        int qa = q0w + (ln >> 4) * 4 + r;
                        if (kva > qa) sv[nf][r] = -3.0e38f;
                    }
                }
            }

            // online softmax with T13 defer-rescale (THR = 8 in log2 domain)
#pragma unroll
            for (int r = 0; r < 4; r++) {
                float rm = fmaxf(fmaxf(sv[0][r], sv[1][r]), fmaxf(sv[2][r], sv[3][r]));
                rm = fmaxf(rm, __shfl_xor(rm, 1));
                rm = fmaxf(rm, __shfl_xor(rm, 2));
                rm = fmaxf(rm, __shfl_xor(rm, 4));
                rm = fmaxf(rm, __shfl_xor(rm, 8));
                if (rm > mref[r] + 8.0f) {   // rescale only on real growth
                    float sc = exp2f(mref[r] - rm);
                    mref[r] = rm;
                    lsum[r] *= sc;
#pragma unroll
                    for (int df = 0; df < 8; ++df) o[df][r] *= sc;
                }
                float rs = 0.f;
#pragma unroll
                for (int nf = 0; nf < 4; ++nf) {
                    float p = exp2f(sv[nf][r] - mref[r]);   // bounded by 2^8
                    sv[nf][r] = p;
                    rs += p;
                }
                rs += __shfl_xor(rs, 1); rs += __shfl_xor(rs, 2);
                rs += __shfl_xor(rs, 4); rs += __shfl_xor(rs, 8);
                lsum[r] += rs;
            }

            // P -> per-wave LDS (bf16), then PV
            u16* pw = Pl[w];
#pragma unroll
            for (int nf = 0; nf < 4; ++nf)
#pragma unroll
                for (int r = 0; r < 4; r++)
                    pw[((ln >> 4) * 4 + r) * 72 + nf * 16 + (ln & 15)] = f2bf(sv[nf][r]);

#pragma unroll
            for (int kc = 0; kc < 2; ++kc) {
                bf16x8 a = *(const bf16x8*)(pw + (ln & 15) * 72 + kc * 32 + (ln >> 4) * 8);
                __builtin_amdgcn_s_setprio(1);
#pragma unroll
                for (int df = 0; df < 8; ++df) {
                    int d = df * 16 + (ln & 15);
                    int by = (d * 128 + kc * 64 + (ln >> 4) * 16) ^ ((d & 7) << 4);
                    bf16x8 vb = *(const bf16x8*)((const char*)Vs[cur] + by);
                    o[df] = __builtin_amdgcn_mfma_f32_16x16x32_bf16(a, vb, o[df], 0, 0, 0);
                }
                __builtin_amdgcn_s_setprio(0);
            }

            if (more) {
                __syncthreads();
                writebuf(cur ^ 1);
                __syncthreads();
                cur ^= 1;
            }
        }

        // finalize tile t
#pragma unroll
        for (int r = 0; r < 4; ++r) lsum[r] = 1.0f / lsum[r];
#pragma unroll
        for (int df = 0; df < 8; ++df)
#pragma unroll
            for (int r = 0; r < 4; r++) {
                int qa = q0w + (ln >> 4) * 4 + r;
                ctx[(size_t)(b * 2048 + qa) * 2048 + h * 128 + df * 16 + (ln & 15)] =
                    f2bf(o[df][r] * lsum[r]);
            }
    }
}

// ---------------------------------------------------------------------------
extern "C" void kernel_launch(void* const* d_in, const int* in_sizes, int n_in,
                              void* d_out, int out_size, void* d_ws, size_t ws_size,
                              hipStream_t stream) {
    const float* x  = (const float*)d_in[0];
    const float* wq = (const float*)d_in[1];
    const float* wk = (const float*)d_in[2];
    const float* wv = (const float*)d_in[3];
    const float* wo = (const float*)d_in[4];
    float* out = (float*)d_out;

    u16* ws  = (u16*)d_ws;
    u16* xb  = ws;                     //  8,388,608 : x bf16 (4096x2048)
    u16* wt  = xb + 8388608;           // 16,777,216 : WqT|WkT|WvT|WoT bf16
    u16* qkb = wt + 16777216;          // 16,777,216 : [Q*scale | K] (4096x4096)
    u16* vtb = qkb + 16777216;         //  8,388,608 : V^T (2048x4096)
    u16* ctx = vtb + 8388608;          //  8,388,608 : attention out (4096x2048)

    cvt_x_k<<<8192, 256, 0, stream>>>(x, xb);
    wcvt_k<<<dim3(64, 64, 4), dim3(32, 8), 0, stream>>>(wq, wk, wv, wo, wt);
    gemm_qkv_k<<<dim3(32, 48), 256, 0, stream>>>(xb, wt, qkb, vtb);   // Q|K|V fused
    attn_k<<<512, 256, 0, stream>>>(qkb, vtb, ctx);
    gemm_out_k<<<dim3(32, 16), 256, 0, stream>>>(ctx, wt + 3 * 4194304, out);
}

// Round 7
// 431.304 us; speedup vs baseline: 1.0414x; 1.0194x over previous
//
#include <hip/hip_runtime.h>

// ---------------------------------------------------------------------------
// Attention block on MI355X (gfx950), bf16-MFMA pipeline.
// R7: GEMMs rebuilt as 256x128x64 triple-buffered counted-vmcnt pipeline
// (T2 swizzle + T4 counted vmcnt + T5 setprio, raw s_barrier). Triple buffer
// makes buffer hand-off provably race-free:
//   - write(k+2) issued after the barrier sealing reads(k-1) [same buffer]
//   - read(k) preceded by each wave's own vmcnt(6) BEFORE the barrier, so the
//     barrier publishes "all waves' K-tile-k loads landed".
// attn / cvt kernels unchanged from R6.
// ---------------------------------------------------------------------------

typedef unsigned short u16;
using bf16x8 = __attribute__((ext_vector_type(8))) short;   // 8 bf16 (4 VGPRs)
using f32x4  = __attribute__((ext_vector_type(4))) float;
using u16x8  = __attribute__((ext_vector_type(8))) unsigned short;
using u16x4  = __attribute__((ext_vector_type(4))) unsigned short;

#define AS1 __attribute__((address_space(1)))
#define AS3 __attribute__((address_space(3)))

__device__ __forceinline__ u16 f2bf(float f) {
    union { float f; unsigned u; } v; v.f = f;
    unsigned r = v.u + 0x7fffu + ((v.u >> 16) & 1u);   // RNE
    return (u16)(r >> 16);
}

__device__ __forceinline__ void gload_lds16(const void* g, void* l) {
    __builtin_amdgcn_global_load_lds((const AS1 void*)g, (AS3 void*)l, 16, 0, 0);
}

// ---------------- x -> bf16 ----------------
__global__ __launch_bounds__(256) void cvt_x_k(const float* __restrict__ x,
                                               u16* __restrict__ xb) {
    int i = (blockIdx.x * 256 + threadIdx.x) * 4;
    float4 v = *(const float4*)(x + i);
    u16x4 o;
    o[0] = f2bf(v.x); o[1] = f2bf(v.y); o[2] = f2bf(v.z); o[3] = f2bf(v.w);
    *(u16x4*)(xb + i) = o;
}

// ---------------- weights -> bf16, transposed (WT[n][k]) ----------------
__global__ __launch_bounds__(256) void wcvt_k(const float* __restrict__ Wq,
                                              const float* __restrict__ Wk,
                                              const float* __restrict__ Wv,
                                              const float* __restrict__ Wo,
                                              u16* __restrict__ wt) {
    __shared__ float tile[32][33];
    const int z = blockIdx.z;
    const float* W = (z == 0) ? Wq : (z == 1) ? Wk : (z == 2) ? Wv : Wo;
    const float scale = (z == 0) ? 0.12751744f : 1.0f;  // (1/sqrt(128))*log2(e)
    const int tx = threadIdx.x, ty = threadIdx.y;       // block (32,8)
    const int k0 = blockIdx.x * 32, n0 = blockIdx.y * 32;
#pragma unroll
    for (int j = 0; j < 4; j++)
        tile[ty + j * 8][tx] = W[(size_t)(k0 + ty + j * 8) * 2048 + n0 + tx];
    __syncthreads();
    u16* dst = wt + (size_t)z * 4194304;
#pragma unroll
    for (int j = 0; j < 4; j++)
        dst[(size_t)(n0 + ty + j * 8) * 2048 + k0 + tx] = f2bf(tile[tx][ty + j * 8] * scale);
}

// ---------------- pipelined GEMM: 256x128 tile, BK=64, triple-buffered -----
// C(M x N) = A(M x 2048) * BT(N x 2048)^T, K = 2048 (32 K-tiles).
// 512 threads = 8 waves (2M x 4N); per-wave output 128x32.
// LDS: As 3x32KB + Bs 3x16KB = 144KB -> 1 block/CU, 2 waves/SIMD.
// EPI 0: dual epilogue (n0<4096 -> qkb bf16 [m][n]; else vtb bf16 [n-4096][m])
// EPI 1: f32 C[m][2048+n]... no: plain f32 C[m*2048+n].
template <int EPI>
__global__ __launch_bounds__(512, 2) void gemm256_k(const u16* __restrict__ A,
                                                    const u16* __restrict__ BT,
                                                    u16* __restrict__ qkb,
                                                    u16* __restrict__ vtb,
                                                    float* __restrict__ Cf) {
    constexpr int NK = 32;                 // 2048 / 64
    __shared__ u16 As[3][16384];           // [buf][256 rows][64 k] bf16, swizzled
    __shared__ u16 Bs[3][8192];            // [buf][128 rows][64 k]
    const int tid = threadIdx.x, ln = tid & 63, w = tid >> 6;
    const int wm = w >> 2, wn = w & 3;
    const int m0 = blockIdx.x * 256, n0 = blockIdx.y * 128;

    // staging geometry: chunk = 64 rows x 64 k = 8KB = one 512-thread gload.
    // LDS dest is linear; swizzle (slot ^= row&7) applied on the GLOBAL source
    // so that LDS[r][s] = G[gr][(s^(r&7))*8 ..] (rule #21: involution XOR).
    const int srow = tid >> 3;                          // row within chunk
    const int scol = ((tid & 7) ^ (srow & 7)) * 8;      // pre-swizzled col
    const u16* Ag = A + (size_t)(m0 + srow) * 2048 + scol;
    const u16* Bg = BT + (size_t)(n0 + srow) * 2048 + scol;

    f32x4 acc[8][2] = {};

    auto stage = [&](int kt) {
        const int bi = kt % 3;
        const size_t ko = (size_t)kt * 64;
        char* Ad = (char*)As[bi] + w * 1024;            // wave-uniform base
        char* Bd = (char*)Bs[bi] + w * 1024;
#pragma unroll
        for (int c = 0; c < 4; ++c)
            gload_lds16(Ag + (size_t)c * 64 * 2048 + ko, Ad + c * 8192);
#pragma unroll
        for (int c = 0; c < 2; ++c)
            gload_lds16(Bg + (size_t)c * 64 * 2048 + ko, Bd + c * 8192);
    };

    stage(0);
    stage(1);

    for (int k = 0; k < NK; ++k) {
        const int bi = k % 3;
        // my reads of iter k-1 serviced, my K-tile-k loads landed -> barrier
        asm volatile("s_waitcnt lgkmcnt(0)" ::: "memory");
        if (k + 1 < NK) asm volatile("s_waitcnt vmcnt(6)" ::: "memory");
        else            asm volatile("s_waitcnt vmcnt(0)" ::: "memory");
        __builtin_amdgcn_sched_barrier(0);
        __builtin_amdgcn_s_barrier();
        __builtin_amdgcn_sched_barrier(0);
        if (k + 2 < NK) stage(k + 2);      // buf (k+2)%3 == (k-1)%3: sealed above
        __builtin_amdgcn_sched_barrier(0);

        const char* Ab = (const char*)As[bi];
        const char* Bb = (const char*)Bs[bi];
#pragma unroll
        for (int kk = 0; kk < 2; ++kk) {
            bf16x8 av[8], bv[2];
#pragma unroll
            for (int i = 0; i < 8; ++i) {
                int R = wm * 128 + i * 16 + (ln & 15);
                int s = (kk * 4 + (ln >> 4)) ^ (R & 7);
                av[i] = *(const bf16x8*)(Ab + R * 128 + s * 16);
            }
#pragma unroll
            for (int j = 0; j < 2; ++j) {
                int R = wn * 32 + j * 16 + (ln & 15);
                int s = (kk * 4 + (ln >> 4)) ^ (R & 7);
                bv[j] = *(const bf16x8*)(Bb + R * 128 + s * 16);
            }
            __builtin_amdgcn_s_setprio(1);
#pragma unroll
            for (int i = 0; i < 8; ++i)
#pragma unroll
                for (int j = 0; j < 2; ++j)
                    acc[i][j] = __builtin_amdgcn_mfma_f32_16x16x32_bf16(av[i], bv[j], acc[i][j], 0, 0, 0);
            __builtin_amdgcn_s_setprio(0);
        }
    }

    // epilogue
    if (EPI == 0) {
        if (n0 < 4096) {          // Q|K -> qkb [m][n], ldc 4096
#pragma unroll
            for (int i = 0; i < 8; ++i)
#pragma unroll
                for (int j = 0; j < 2; ++j)
#pragma unroll
                    for (int r = 0; r < 4; ++r)
                        qkb[(size_t)(m0 + wm * 128 + i * 16 + (ln >> 4) * 4 + r) * 4096 +
                            (n0 + wn * 32 + j * 16 + (ln & 15))] = f2bf(acc[i][j][r]);
        } else {                  // V -> vtb [n-4096][m] (transposed), ldc 4096
            const int n0r = n0 - 4096;
#pragma unroll
            for (int i = 0; i < 8; ++i)
#pragma unroll
                for (int j = 0; j < 2; ++j) {
                    u16x4 pk;
#pragma unroll
                    for (int r = 0; r < 4; ++r) pk[r] = f2bf(acc[i][j][r]);
                    *(u16x4*)(vtb + (size_t)(n0r + wn * 32 + j * 16 + (ln & 15)) * 4096 +
                              (m0 + wm * 128 + i * 16 + (ln >> 4) * 4)) = pk;
                }
        }
    } else {                      // f32 C [m][n], ldc 2048
#pragma unroll
        for (int i = 0; i < 8; ++i)
#pragma unroll
            for (int j = 0; j < 2; ++j)
#pragma unroll
                for (int r = 0; r < 4; ++r)
                    Cf[(size_t)(m0 + wm * 128 + i * 16 + (ln >> 4) * 4 + r) * 2048 +
                       (n0 + wn * 32 + j * 16 + (ln & 15))] = acc[i][j][r];
    }
}

// ---------------- flash attention v3 (paired q-tiles + prefetch + T13) -----
// qk: (4096)x4096 bf16, cols [0,2048)=Q*scale(log2e), [2048,4096)=K
// vt: (2048 = h*128+d) x 4096 bf16  (V^T)
// ctx: (4096)x2048 bf16
__global__ __launch_bounds__(256, 2) void attn_k(const u16* __restrict__ qk,
                                                 const u16* __restrict__ vt,
                                                 u16* __restrict__ ctx) {
    const int bid = blockIdx.x;
    const int xcd = bid & 7, idx = bid >> 3;     // XCD-grouped decode
    const int bh = xcd * 4 + (idx & 3);          // 4 (b,h) groups per XCD
    const int qp = idx >> 2;                     // 0..15
    const int b = bh >> 4, h = bh & 15;
    const int qtA = qp, qtB = 31 - qp;
    const int tid = threadIdx.x, ln = tid & 63, w = tid >> 6;

    __shared__ u16 Ks[2][8192];     // [64][128] bf16, XOR-swizzled
    __shared__ u16 Vs[2][8192];     // [128][64] bf16, XOR-swizzled
    __shared__ u16 Pl[4][16 * 72];  // per-wave P tile [q][kv], pad 8

    const u16* Kg = qk + (size_t)(b * 2048) * 4096 + 2048 + h * 128;  // +t*4096+d
    const u16* Vg = vt + (size_t)(h * 128) * 4096 + b * 2048;         // +d*4096+t

    const int nstA = qtA + 1;
    const int nst = 33;

    const int skr = tid >> 4, skc = (tid & 15) * 8;   // K: row skr+p*16, col skc
    const int svd = tid >> 3, svc = (tid & 7) * 8;    // V: d svd+p*32, col svc

    u16x8 rg[8];
    auto issue = [&](int s) {
        const int kv0 = (s < nstA ? s : s - nstA) * 64;
#pragma unroll
        for (int p = 0; p < 4; ++p)
            rg[p] = *(const u16x8*)(Kg + (size_t)(kv0 + p * 16 + skr) * 4096 + skc);
#pragma unroll
        for (int p = 0; p < 4; ++p)
            rg[4 + p] = *(const u16x8*)(Vg + (size_t)(p * 32 + svd) * 4096 + kv0 + svc);
    };
    auto writebuf = [&](int bi) {
#pragma unroll
        for (int p = 0; p < 4; ++p) {
            int r = p * 16 + skr;
            int by = (r * 256 + skc * 2) ^ ((r & 7) << 4);
            *(u16x8*)((char*)Ks[bi] + by) = rg[p];
        }
#pragma unroll
        for (int p = 0; p < 4; ++p) {
            int d = p * 32 + svd;
            int by = (d * 128 + svc * 2) ^ ((d & 7) << 4);
            *(u16x8*)((char*)Vs[bi] + by) = rg[4 + p];
        }
    };

    issue(0);
    writebuf(0);
    __syncthreads();
    int cur = 0, s = 0;

    for (int t = 0; t < 2; ++t) {
        const int qt = (t == 0) ? qtA : qtB;
        const int q0w = qt * 64 + w * 16;
        bf16x8 qf[4];
        {
            const u16* qb = qk + (size_t)(b * 2048 + q0w + (ln & 15)) * 4096 +
                            h * 128 + (ln >> 4) * 8;
#pragma unroll
            for (int kc = 0; kc < 4; ++kc) qf[kc] = *(const bf16x8*)(qb + kc * 32);
        }
        f32x4 o[8] = {};
        float mref[4], lsum[4];
#pragma unroll
        for (int r = 0; r < 4; ++r) { mref[r] = -3.0e38f; lsum[r] = 0.f; }

        for (int kb = 0; kb <= qt; ++kb, ++s) {
            const bool more = (s + 1 < nst);
            if (more) issue(s + 1);          // prefetch next tile into regs
            const int kv0 = kb * 64;

            // S = Q K^T (16 q-rows x 64 kv per wave), log2 domain
            f32x4 sv[4] = {};
            __builtin_amdgcn_s_setprio(1);
#pragma unroll
            for (int kc = 0; kc < 4; ++kc)
#pragma unroll
                for (int nf = 0; nf < 4; ++nf) {
                    int row = nf * 16 + (ln & 15);
                    int by = (row * 256 + kc * 64 + (ln >> 4) * 16) ^ ((row & 7) << 4);
                    bf16x8 kf = *(const bf16x8*)((const char*)Ks[cur] + by);
                    sv[nf] = __builtin_amdgcn_mfma_f32_16x16x32_bf16(qf[kc], kf, sv[nf], 0, 0, 0);
                }
            __builtin_amdgcn_s_setprio(0);

            if (kb == qt) {  // causal mask on diagonal block
#pragma unroll
                for (int nf = 0; nf < 4; ++nf) {
                    int kva = kv0 + nf * 16 + (ln & 15);
#pragma unroll
                    for (int r = 0; r < 4; r++) {
                        int qa = q0w + (ln >> 4) * 4 + r;
                        if (kva > qa) sv[nf][r] = -3.0e38f;
                    }
                }
            }

            // online softmax with T13 defer-rescale (THR = 8 in log2 domain)
#pragma unroll
            for (int r = 0; r < 4; r++) {
                float rm = fmaxf(fmaxf(sv[0][r], sv[1][r]), fmaxf(sv[2][r], sv[3][r]));
                rm = fmaxf(rm, __shfl_xor(rm, 1));
                rm = fmaxf(rm, __shfl_xor(rm, 2));
                rm = fmaxf(rm, __shfl_xor(rm, 4));
                rm = fmaxf(rm, __shfl_xor(rm, 8));
                if (rm > mref[r] + 8.0f) {   // rescale only on real growth
                    float sc = exp2f(mref[r] - rm);
                    mref[r] = rm;
                    lsum[r] *= sc;
#pragma unroll
                    for (int df = 0; df < 8; ++df) o[df][r] *= sc;
                }
                float rs = 0.f;
#pragma unroll
                for (int nf = 0; nf < 4; ++nf) {
                    float p = exp2f(sv[nf][r] - mref[r]);   // bounded by 2^8
                    sv[nf][r] = p;
                    rs += p;
                }
                rs += __shfl_xor(rs, 1); rs += __shfl_xor(rs, 2);
                rs += __shfl_xor(rs, 4); rs += __shfl_xor(rs, 8);
                lsum[r] += rs;
            }

            // P -> per-wave LDS (bf16), then PV
            u16* pw = Pl[w];
#pragma unroll
            for (int nf = 0; nf < 4; ++nf)
#pragma unroll
                for (int r = 0; r < 4; r++)
                    pw[((ln >> 4) * 4 + r) * 72 + nf * 16 + (ln & 15)] = f2bf(sv[nf][r]);

#pragma unroll
            for (int kc = 0; kc < 2; ++kc) {
                bf16x8 a = *(const bf16x8*)(pw + (ln & 15) * 72 + kc * 32 + (ln >> 4) * 8);
                __builtin_amdgcn_s_setprio(1);
#pragma unroll
                for (int df = 0; df < 8; ++df) {
                    int d = df * 16 + (ln & 15);
                    int by = (d * 128 + kc * 64 + (ln >> 4) * 16) ^ ((d & 7) << 4);
                    bf16x8 vb = *(const bf16x8*)((const char*)Vs[cur] + by);
                    o[df] = __builtin_amdgcn_mfma_f32_16x16x32_bf16(a, vb, o[df], 0, 0, 0);
                }
                __builtin_amdgcn_s_setprio(0);
            }

            if (more) {
                __syncthreads();
                writebuf(cur ^ 1);
                __syncthreads();
                cur ^= 1;
            }
        }

        // finalize tile t
#pragma unroll
        for (int r = 0; r < 4; ++r) lsum[r] = 1.0f / lsum[r];
#pragma unroll
        for (int df = 0; df < 8; ++df)
#pragma unroll
            for (int r = 0; r < 4; r++) {
                int qa = q0w + (ln >> 4) * 4 + r;
                ctx[(size_t)(b * 2048 + qa) * 2048 + h * 128 + df * 16 + (ln & 15)] =
                    f2bf(o[df][r] * lsum[r]);
            }
    }
}

// ---------------------------------------------------------------------------
extern "C" void kernel_launch(void* const* d_in, const int* in_sizes, int n_in,
                              void* d_out, int out_size, void* d_ws, size_t ws_size,
                              hipStream_t stream) {
    const float* x  = (const float*)d_in[0];
    const float* wq = (const float*)d_in[1];
    const float* wk = (const float*)d_in[2];
    const float* wv = (const float*)d_in[3];
    const float* wo = (const float*)d_in[4];
    float* out = (float*)d_out;

    u16* ws  = (u16*)d_ws;
    u16* xb  = ws;                     //  8,388,608 : x bf16 (4096x2048)
    u16* wt  = xb + 8388608;           // 16,777,216 : WqT|WkT|WvT|WoT bf16
    u16* qkb = wt + 16777216;          // 16,777,216 : [Q*scale | K] (4096x4096)
    u16* vtb = qkb + 16777216;         //  8,388,608 : V^T (2048x4096)
    u16* ctx = vtb + 8388608;          //  8,388,608 : attention out (4096x2048)

    cvt_x_k<<<8192, 256, 0, stream>>>(x, xb);
    wcvt_k<<<dim3(64, 64, 4), dim3(32, 8), 0, stream>>>(wq, wk, wv, wo, wt);
    gemm256_k<0><<<dim3(16, 48), 512, 0, stream>>>(xb, wt, qkb, vtb, nullptr);  // Q|K|V
    attn_k<<<512, 256, 0, stream>>>(qkb, vtb, ctx);
    gemm256_k<1><<<dim3(16, 16), 512, 0, stream>>>(ctx, wt + 3 * 4194304,
                                                   nullptr, nullptr, out);      // out-proj
}